// Round 3
// baseline (922.046 us; speedup 1.0000x reference)
//
#include <hip/hip_runtime.h>
#include <math.h>
#include <float.h>

#define NROWS 10000
#define INDIM 512
#define KSPLIT 384    // OpenBLAS sgemm GEMM_Q (Haswell/Zen): k=512 -> chain(0:384)+chain(384:512)
#define HID   128
#define TKEEP 16      // per-strip candidates kept per row
#define KOUT  14      // k-1 off-diagonal outputs per row
#define BM    32
#define BN    64
#define NSTRIP 4
#define STRIPW 2500

// ---------------------------------------------------------------------------
// K1: bit-replicate numpy f32:  z = sgemm(feat,W) + b ;  n = max(||z||,1e-12)
//     zhat = z / n.  sgemm chain: sequential f32 FMA over k, kc-split at 384.
//     norm: pairwise-8 sum of rounded squares (numpy add.reduce, n=128 path).
// block = 128 threads (one per hidden unit), 16 rows per block, grid = 625
// ---------------------------------------------------------------------------
__global__ __launch_bounds__(128)
void k_projnorm(const float* __restrict__ feat, const float* __restrict__ W,
                const float* __restrict__ b, float* __restrict__ z32) {
    const int h = threadIdx.x;          // 0..127
    const int row0 = blockIdx.x * 16;
    float accA[16], accB[16];
#pragma unroll
    for (int r = 0; r < 16; ++r) { accA[r] = 0.f; accB[r] = 0.f; }
    for (int k = 0; k < KSPLIT; ++k) {
        const float w = W[k * HID + h];
#pragma unroll
        for (int r = 0; r < 16; ++r)
            accA[r] = fmaf(feat[(size_t)(row0 + r) * INDIM + k], w, accA[r]);
    }
    for (int k = KSPLIT; k < INDIM; ++k) {
        const float w = W[k * HID + h];
#pragma unroll
        for (int r = 0; r < 16; ++r)
            accB[r] = fmaf(feat[(size_t)(row0 + r) * INDIM + k], w, accB[r]);
    }
    __shared__ float zl[16][HID];       // 8 KB
    __shared__ float nrm[16];
    const float bh = b[h];
#pragma unroll
    for (int r = 0; r < 16; ++r)
        zl[r][h] = __fadd_rn(__fadd_rn(accA[r], accB[r]), bh);  // (blk1+blk2)+b, each rounded
    __syncthreads();
    if (h < 16) {
        float rr[8];
#pragma unroll
        for (int j = 0; j < 8; ++j) rr[j] = __fmul_rn(zl[h][j], zl[h][j]);
        for (int i = 8; i < HID; i += 8)
#pragma unroll
            for (int j = 0; j < 8; ++j)
                rr[j] = __fadd_rn(rr[j], __fmul_rn(zl[h][i + j], zl[h][i + j]));
        const float s = __fadd_rn(
            __fadd_rn(__fadd_rn(rr[0], rr[1]), __fadd_rn(rr[2], rr[3])),
            __fadd_rn(__fadd_rn(rr[4], rr[5]), __fadd_rn(rr[6], rr[7])));
        nrm[h] = fmaxf(__fsqrt_rn(s), 1e-12f);
    }
    __syncthreads();
#pragma unroll
    for (int r = 0; r < 16; ++r)
        z32[(size_t)(row0 + r) * HID + h] = __fdiv_rn(zl[r][h], nrm[r]);
}

// ---------------------------------------------------------------------------
// K2: sim = z@z.T per element = sequential f32 FMA chain over k=0..127
//     (bit-exact vs BLAS single-kc-block sgemm). Per-thread sorted top-16 +
//     16-lane tournament merge -> per-strip top-16 by (val desc, idx asc).
// grid = (313, 4), block = 256.
// ---------------------------------------------------------------------------
__global__ __launch_bounds__(256)
void k_simselect(const float* __restrict__ z, float* __restrict__ cval,
                 int* __restrict__ cidx) {
    __shared__ float At[HID][BM];   // 16 KB
    __shared__ float Bt[HID][BN];   // 32 KB
    const int tid = threadIdx.x;
    const int row0 = blockIdx.x * BM;
    const int jbase = blockIdx.y * STRIPW;
    const int ty = tid >> 4;        // 0..15 : owns rows ty*2, ty*2+1
    const int tx = tid & 15;        // 0..15 : owns 4 cols per chunk

    {
        const int r = tid >> 3;
        const int kb = (tid & 7) * 16;
        const int grow = row0 + r;
#pragma unroll
        for (int m = 0; m < 16; m += 4) {
            float4 v = make_float4(0.f, 0.f, 0.f, 0.f);
            if (grow < NROWS) v = *(const float4*)(z + (size_t)grow * HID + kb + m);
            At[kb + m + 0][r] = v.x;
            At[kb + m + 1][r] = v.y;
            At[kb + m + 2][r] = v.z;
            At[kb + m + 3][r] = v.w;
        }
    }

    float tv[2][TKEEP];
    int   ti[2][TKEEP];
#pragma unroll
    for (int r = 0; r < 2; ++r)
#pragma unroll
        for (int s = 0; s < TKEEP; ++s) { tv[r][s] = -INFINITY; ti[r][s] = 0x7fffffff; }

    const int grow0 = row0 + ty * 2;
    const int grow1 = grow0 + 1;

    for (int jc = 0; jc < STRIPW; jc += BN) {
        __syncthreads();
        {
            const int c = tid >> 2;
            const int q = tid & 3;
            const int j = jbase + jc + c;
            const bool okj = (jc + c) < STRIPW;
#pragma unroll
            for (int m = 0; m < 32; m += 4) {
                const int kk = q * 32 + m;
                float4 v = make_float4(0.f, 0.f, 0.f, 0.f);
                if (okj) v = *(const float4*)(z + (size_t)j * HID + kk);
                Bt[kk + 0][c] = v.x;
                Bt[kk + 1][c] = v.y;
                Bt[kk + 2][c] = v.z;
                Bt[kk + 3][c] = v.w;
            }
        }
        __syncthreads();

        // sequential f32 FMA chain over k — bit-exact BLAS inner product
        float acc[2][4] = {{0.f,0.f,0.f,0.f},{0.f,0.f,0.f,0.f}};
#pragma unroll 8
        for (int k = 0; k < HID; ++k) {
            const float2 a  = *(const float2*)&At[k][ty * 2];
            const float4 bb = *(const float4*)&Bt[k][tx * 4];
            acc[0][0] = fmaf(a.x, bb.x, acc[0][0]);
            acc[0][1] = fmaf(a.x, bb.y, acc[0][1]);
            acc[0][2] = fmaf(a.x, bb.z, acc[0][2]);
            acc[0][3] = fmaf(a.x, bb.w, acc[0][3]);
            acc[1][0] = fmaf(a.y, bb.x, acc[1][0]);
            acc[1][1] = fmaf(a.y, bb.y, acc[1][1]);
            acc[1][2] = fmaf(a.y, bb.z, acc[1][2]);
            acc[1][3] = fmaf(a.y, bb.w, acc[1][3]);
        }

#pragma unroll
        for (int r = 0; r < 2; ++r) {
            const int grow = r ? grow1 : grow0;
#pragma unroll
            for (int c = 0; c < 4; ++c) {
                const int loc = jc + tx * 4 + c;
                const int jj = jbase + loc;
                const float val = acc[r][c];
                const bool ok = (loc < STRIPW) && (jj != grow);
                if (ok && val > tv[r][TKEEP - 1]) {
                    float cv = val; int ci = jj;
#pragma unroll
                    for (int s = 0; s < TKEEP; ++s) {
                        const bool gt = cv > tv[r][s];
                        const float dv = gt ? tv[r][s] : cv;
                        const int   di = gt ? ti[r][s] : ci;
                        tv[r][s] = gt ? cv : tv[r][s];
                        ti[r][s] = gt ? ci : ti[r][s];
                        cv = dv; ci = di;
                    }
                }
            }
        }
    }

    // 16-way tournament merge (lex max by value desc, idx asc)
#pragma unroll
    for (int r = 0; r < 2; ++r) {
        const int grow = r ? grow1 : grow0;
        for (int t = 0; t < TKEEP; ++t) {
            float mv = tv[r][0]; int mj = ti[r][0]; int mo = tx;
#pragma unroll
            for (int mask = 1; mask <= 8; mask <<= 1) {
                const float ov = __shfl_xor(mv, mask, 64);
                const int   oj = __shfl_xor(mj, mask, 64);
                const int   oo = __shfl_xor(mo, mask, 64);
                const bool take = (ov > mv) || (ov == mv && oj < mj);
                mv = take ? ov : mv; mj = take ? oj : mj; mo = take ? oo : mo;
            }
            if (tx == 0 && grow < NROWS) {
                const size_t o = (size_t)grow * (NSTRIP * TKEEP) + blockIdx.y * TKEEP + t;
                cval[o] = mv;
                cidx[o] = mj;
            }
            if (tx == mo) {
#pragma unroll
                for (int s = 0; s < TKEEP - 1; ++s) {
                    tv[r][s] = tv[r][s + 1];
                    ti[r][s] = ti[r][s + 1];
                }
                tv[r][TKEEP - 1] = -INFINITY;
                ti[r][TKEEP - 1] = 0x7fffffff;
            }
        }
    }
}

// ---------------------------------------------------------------------------
// K3: zero 4 output rows, then top-14 of the 64 stored f32 candidates per row
//     by (value desc, idx asc) — same key as np stable argsort — and scatter.
// grid = 2500, block = 256 (1 wave per row).
// ---------------------------------------------------------------------------
__global__ __launch_bounds__(256)
void k_select(const float* __restrict__ cval, const int* __restrict__ cidx,
              float* __restrict__ out) {
    const int tid = threadIdx.x;
    const int w = tid >> 6;
    const int lane = tid & 63;
    const int row0 = blockIdx.x * 4;
    const int row = row0 + w;

    {
        const float4 z4 = make_float4(0.f, 0.f, 0.f, 0.f);
        float* base = out + (size_t)row0 * NROWS;
        for (int i = tid; i < 10000; i += 256)
            *(float4*)(base + (size_t)i * 4) = z4;
    }

    const float v  = cval[(size_t)row * (NSTRIP * TKEEP) + lane];
    const int  idx = cidx[(size_t)row * (NSTRIP * TKEEP) + lane];

    __syncthreads();   // drain zero-stores (vmcnt(0) before barrier) before scatter

    bool alive = true;
    for (int t = 0; t < KOUT; ++t) {
        float mv = alive ? v : -INFINITY;
        int   mj = alive ? idx : 0x7fffffff;
#pragma unroll
        for (int mask = 1; mask <= 32; mask <<= 1) {
            const float ov = __shfl_xor(mv, mask, 64);
            const int   oj = __shfl_xor(mj, mask, 64);
            const bool take = (ov > mv) || (ov == mv && oj < mj);
            mv = take ? ov : mv; mj = take ? oj : mj;
        }
        if (alive && idx == mj) {
            out[(size_t)row * NROWS + idx] = v;
            alive = false;
        }
    }
}

// ---------------------------------------------------------------------------
extern "C" void kernel_launch(void* const* d_in, const int* in_sizes, int n_in,
                              void* d_out, int out_size, void* d_ws, size_t ws_size,
                              hipStream_t stream) {
    const float* feat = (const float*)d_in[0];
    const float* W    = (const float*)d_in[1];
    const float* b    = (const float*)d_in[2];
    float* out = (float*)d_out;

    char* ws = (char*)d_ws;
    float* z32  = (float*)ws;                      // 10000*128*4 = 5,120,000 B
    float* cval = (float*)(ws + 5120000);          // 10000*64*4  = 2,560,000 B
    int*   cidx = (int*)  (ws + 7680000);          // 10000*64*4  = 2,560,000 B

    hipLaunchKernelGGL(k_projnorm,  dim3(625),    dim3(128), 0, stream, feat, W, b, z32);
    hipLaunchKernelGGL(k_simselect, dim3(313, 4), dim3(256), 0, stream, z32, cval, cidx);
    hipLaunchKernelGGL(k_select,    dim3(2500),   dim3(256), 0, stream, cval, cidx, out);
}

// Round 4
// 619.377 us; speedup vs baseline: 1.4887x; 1.4887x over previous
//
#include <hip/hip_runtime.h>
#include <hip/hip_bf16.h>
#include <math.h>
#include <float.h>

#define NROWS 10000
#define INDIM 512
#define KSPLIT 384    // OpenBLAS sgemm kc split (passed Round 3 — do not touch)
#define HID   128
#define NSTRIP 4
#define STRIPW 2500
#define CHUNK 64
#define NCHUNK 40     // 40*64 = 2560 >= 2500
#define ZPADR 10240   // padded z_bf16 rows (strip overrun reads land in zero pad)
#define LLEN  16      // per-lane candidate list
#define KSTR  32      // candidates kept per (row, strip)
#define NCAND 128     // 4 strips * 32
#define KOUT  14
#define Z4TOT 25000000UL   // 10000*10000/4 float4s of output
#define Z4BLK 39809UL      // ceil(Z4TOT/628)
#define Z4CHK 996          // ceil(Z4BLK/NCHUNK)

using short8 = __attribute__((ext_vector_type(8))) short;  // 8 bf16 (4 VGPR)
using f32x4  = __attribute__((ext_vector_type(4))) float;

// ---------------------------------------------------------------------------
// K1: bit-replicates numpy f32 (unchanged from passing Round 3) + emits bf16
// copy of zhat for the MFMA candidate kernel. grid = 640 (15 pad blocks).
// ---------------------------------------------------------------------------
__global__ __launch_bounds__(128)
void k_projnorm(const float* __restrict__ feat, const float* __restrict__ W,
                const float* __restrict__ b, float* __restrict__ z32,
                __hip_bfloat16* __restrict__ zb) {
    const int h = threadIdx.x;
    const int row0 = blockIdx.x * 16;
    if (row0 >= NROWS) {   // zero the bf16 pad rows (keeps strip-overrun reads clean)
#pragma unroll
        for (int r = 0; r < 16; ++r)
            zb[(size_t)(row0 + r) * HID + h] = __float2bfloat16(0.f);
        return;
    }
    float accA[16], accB[16];
#pragma unroll
    for (int r = 0; r < 16; ++r) { accA[r] = 0.f; accB[r] = 0.f; }
    for (int k = 0; k < KSPLIT; ++k) {
        const float w = W[k * HID + h];
#pragma unroll
        for (int r = 0; r < 16; ++r)
            accA[r] = fmaf(feat[(size_t)(row0 + r) * INDIM + k], w, accA[r]);
    }
    for (int k = KSPLIT; k < INDIM; ++k) {
        const float w = W[k * HID + h];
#pragma unroll
        for (int r = 0; r < 16; ++r)
            accB[r] = fmaf(feat[(size_t)(row0 + r) * INDIM + k], w, accB[r]);
    }
    __shared__ float zl[16][HID];
    __shared__ float nrm[16];
    const float bh = b[h];
#pragma unroll
    for (int r = 0; r < 16; ++r)
        zl[r][h] = __fadd_rn(__fadd_rn(accA[r], accB[r]), bh);
    __syncthreads();
    if (h < 16) {
        float rr[8];
#pragma unroll
        for (int j = 0; j < 8; ++j) rr[j] = __fmul_rn(zl[h][j], zl[h][j]);
        for (int i = 8; i < HID; i += 8)
#pragma unroll
            for (int j = 0; j < 8; ++j)
                rr[j] = __fadd_rn(rr[j], __fmul_rn(zl[h][i + j], zl[h][i + j]));
        const float s = __fadd_rn(
            __fadd_rn(__fadd_rn(rr[0], rr[1]), __fadd_rn(rr[2], rr[3])),
            __fadd_rn(__fadd_rn(rr[4], rr[5]), __fadd_rn(rr[6], rr[7])));
        nrm[h] = fmaxf(__fsqrt_rn(s), 1e-12f);
    }
    __syncthreads();
#pragma unroll
    for (int r = 0; r < 16; ++r) {
        const float v = __fdiv_rn(zl[r][h], nrm[r]);
        z32[(size_t)(row0 + r) * HID + h] = v;
        zb [(size_t)(row0 + r) * HID + h] = __float2bfloat16(v);
    }
}

// ---------------------------------------------------------------------------
// K2: bf16 MFMA candidate generator + fused output zeroing.
// grid = (157, 4), block 256 (4 waves, 16 rows each -> 64 rows/block).
// Per chunk: stage 64 j-rows of bf16 z into XOR-swizzled LDS, 16 mfma,
// dump C to LDS (swizzled), per-lane top-16 insertion (4 lanes per row),
// plus 996 float4 zero-stores of the output (drained by chunk barrier).
// End: 4-lane tournament -> top-32 indices per (row, strip).
// ---------------------------------------------------------------------------
__global__ __launch_bounds__(256)
void k_cand(const __hip_bfloat16* __restrict__ zbp, float4* __restrict__ out4,
            int* __restrict__ cidx) {
    __shared__ ushort Bt[8192];      // 16 KB: [64 j][128 k] bf16, in-row bytes ^ ((j&7)<<4)
    __shared__ float  Cd[4][1024];   // 4 KB/wave: [16 row][64 col] f32, bytes ^ ((row&3)<<4)
    const ushort* zb = (const ushort*)zbp;
    const int tid  = threadIdx.x;
    const int lane = tid & 63;
    const int wid  = tid >> 6;
    const int row0 = blockIdx.x * 64;
    const int jbase = blockIdx.y * STRIPW;
    const int bid = blockIdx.y * gridDim.x + blockIdx.x;

    const int arow  = row0 + wid * 16 + (lane & 15);   // mfma A row (l&15)
    const int row_g = row0 + wid * 16 + (lane >> 2);   // selection row (4 lanes/row)

    // A fragments in registers: lane holds A[arow][ (l>>4)*8 + ks*32 .. +8 ]
    short8 afr[4];
    {
        const ushort* ap = zb + (size_t)arow * HID + ((lane >> 4) * 8);
#pragma unroll
        for (int ks = 0; ks < 4; ++ks)
            afr[ks] = *(const short8*)(ap + ks * 32);
    }

    float tv[LLEN]; int ti[LLEN];
#pragma unroll
    for (int s = 0; s < LLEN; ++s) { tv[s] = -INFINITY; ti[s] = 0x7fffffff; }

    const size_t zbase = (size_t)bid * Z4BLK;
    const float4 zz = make_float4(0.f, 0.f, 0.f, 0.f);

    for (int c = 0; c < NCHUNK; ++c) {
        const int jc = c * CHUNK;
        // ---- stage B chunk: linear global read, swizzled LDS write ----
#pragma unroll
        for (int i = 0; i < 4; ++i) {
            const int off = (wid * 4 + i) * 1024 + lane * 16;   // byte within 16KB
            const int jl = off >> 8;                            // local j 0..63
            const int ir = off & 255;                           // in-row byte
            const uint4 d = *(const uint4*)((const char*)zb +
                              (size_t)(jbase + jc + jl) * 256 + ir);
            *(uint4*)((char*)Bt + (size_t)jl * 256 + (ir ^ ((jl & 7) << 4))) = d;
        }
        // ---- fused output zeroing (streaming stores; drained at barrier) ----
        {
            size_t zend = zbase + Z4BLK; if (zend > Z4TOT) zend = Z4TOT;
            size_t z0 = zbase + (size_t)c * Z4CHK;
            size_t ze = z0 + Z4CHK; if (ze > zend) ze = zend;
            for (size_t i = z0 + tid; i < ze; i += 256) out4[i] = zz;
        }
        __syncthreads();

        // ---- 16 mfma: 4 j-tiles x 4 k-steps ----
        f32x4 acc[4];
#pragma unroll
        for (int t = 0; t < 4; ++t) {
            acc[t] = (f32x4)(0.f);
            const int jl = t * 16 + (lane & 15);
#pragma unroll
            for (int ks = 0; ks < 4; ++ks) {
                const int lo = (ks * 64 + (lane >> 4) * 16) ^ ((lane & 7) << 4);
                const short8 bfr = *(const short8*)((const char*)Bt +
                                     (size_t)jl * 256 + lo);
                acc[t] = __builtin_amdgcn_mfma_f32_16x16x32_bf16(afr[ks], bfr, acc[t],
                                                                 0, 0, 0);
            }
        }
        // ---- dump C to LDS (swizzled): row = (l>>4)*4+r, col = t*16 + (l&15) ----
        {
            float* cd = Cd[wid];
            const int rb = (lane >> 4) * 4;
#pragma unroll
            for (int t = 0; t < 4; ++t) {
                const int col4 = (t * 16 + (lane & 15)) * 4;
#pragma unroll
                for (int r = 0; r < 4; ++r)
                    cd[((rb + r) * 256 + (col4 ^ (r << 4))) >> 2] = acc[t][r];
            }
        }
        // ---- read back own row (4 lanes/row, 16 j each) + insertion ----
        {
            const float* cd = Cd[wid];
            const int rloc = lane >> 2;
#pragma unroll
            for (int i = 0; i < 4; ++i) {
                const int lb = (((lane & 3) * 64 + i * 16) ^ ((rloc & 3) << 4));
                const f32x4 v = *(const f32x4*)((const char*)cd + rloc * 256 + lb);
#pragma unroll
                for (int w = 0; w < 4; ++w) {
                    const int js = jc + (lane & 3) * 16 + i * 4 + w;
                    const int jg = jbase + js;
                    const float val = v[w];
                    const bool ok = (js < STRIPW) && (jg != row_g);
                    if (ok && val > tv[LLEN - 1]) {
                        float cv = val; int ci = jg;
#pragma unroll
                        for (int s = 0; s < LLEN; ++s) {
                            const bool gt = cv > tv[s];
                            const float dv = gt ? tv[s] : cv;
                            const int   di = gt ? ti[s] : ci;
                            tv[s] = gt ? cv : tv[s];
                            ti[s] = gt ? ci : ti[s];
                            cv = dv; ci = di;
                        }
                    }
                }
            }
        }
        __syncthreads();   // protect Bt before next chunk's staging
    }

    // ---- 4-lane tournament per row: pop top-32 indices (membership only) ----
    for (int t = 0; t < KSTR; ++t) {
        float mv = tv[0]; int mj = ti[0];
#pragma unroll
        for (int mask = 1; mask <= 2; mask <<= 1) {
            const float ov = __shfl_xor(mv, mask, 64);
            const int   oj = __shfl_xor(mj, mask, 64);
            const bool take = (ov > mv) || (ov == mv && oj < mj);
            mv = take ? ov : mv; mj = take ? oj : mj;
        }
        if ((lane & 3) == 0 && row_g < NROWS)
            cidx[(size_t)row_g * NCAND + blockIdx.y * KSTR + t] = mj;
        if (ti[0] == mj) {   // unique owner pops
#pragma unroll
            for (int s = 0; s < LLEN - 1; ++s) { tv[s] = tv[s + 1]; ti[s] = ti[s + 1]; }
            tv[LLEN - 1] = -INFINITY; ti[LLEN - 1] = 0x7fffffff;
        }
    }
}

// ---------------------------------------------------------------------------
// K3: exact rescore of 128 candidates/row with the SAME sequential f32 FMA
// chain that passed Round 3 (bitwise-identical values), top-14 by
// (value desc, idx asc), scatter. Output rows already zeroed by K2.
// grid = 2500 (4 rows/block, 1 wave/row, 2 candidates/lane).
// ---------------------------------------------------------------------------
__global__ __launch_bounds__(256)
void k_rescore(const float* __restrict__ z32, const int* __restrict__ cidx,
               float* __restrict__ out) {
    __shared__ float zr[4][HID];
    const int tid = threadIdx.x;
    const int wid = tid >> 6;
    const int lane = tid & 63;
    const int row = blockIdx.x * 4 + wid;

    *(float2*)&zr[wid][lane * 2] = *(const float2*)(z32 + (size_t)row * HID + lane * 2);
    __syncthreads();

    const int c0 = cidx[(size_t)row * NCAND + lane];
    const int c1 = cidx[(size_t)row * NCAND + 64 + lane];
    const float* p0 = z32 + (size_t)c0 * HID;
    const float* p1 = z32 + (size_t)c1 * HID;

    float a0 = 0.f, a1 = 0.f;
#pragma unroll
    for (int k = 0; k < HID; ++k) {      // strict k-ascending chains (bit-exact)
        const float zk = zr[wid][k];
        a0 = fmaf(zk, p0[k], a0);
        a1 = fmaf(zk, p1[k], a1);
    }

    // lane-local sorted pair, then 14 tournament pops over 64 lanes
    const bool sw = (a1 > a0) || (a1 == a0 && c1 < c0);
    float v0 = sw ? a1 : a0, v1 = sw ? a0 : a1;
    int   i0 = sw ? c1 : c0, i1 = sw ? c0 : c1;
    int p = 0;
    for (int t = 0; t < KOUT; ++t) {
        const float ov = (p == 0) ? v0 : ((p == 1) ? v1 : -INFINITY);
        const int   oi = (p == 0) ? i0 : ((p == 1) ? i1 : 0x7fffffff);
        float mv = ov; int mi = oi;
#pragma unroll
        for (int mask = 1; mask <= 32; mask <<= 1) {
            const float xv = __shfl_xor(mv, mask, 64);
            const int   xi = __shfl_xor(mi, mask, 64);
            const bool take = (xv > mv) || (xv == mv && xi < mi);
            mv = take ? xv : mv; mi = take ? xi : mi;
        }
        if (p < 2 && oi == mi) {
            out[(size_t)row * NROWS + mi] = ov;
            ++p;
        }
    }
}

// ---------------------------------------------------------------------------
extern "C" void kernel_launch(void* const* d_in, const int* in_sizes, int n_in,
                              void* d_out, int out_size, void* d_ws, size_t ws_size,
                              hipStream_t stream) {
    const float* feat = (const float*)d_in[0];
    const float* W    = (const float*)d_in[1];
    const float* b    = (const float*)d_in[2];
    float* out = (float*)d_out;

    char* ws = (char*)d_ws;
    float*          z32 = (float*)ws;                         // 5,120,000 B
    __hip_bfloat16* zb  = (__hip_bfloat16*)(ws + 5120000);    // 10240*256 = 2,621,440 B
    int*            cid = (int*)(ws + 7741440);               // 10000*128*4 = 5,120,000 B

    hipLaunchKernelGGL(k_projnorm, dim3(640),    dim3(128), 0, stream, feat, W, b, z32, zb);
    hipLaunchKernelGGL(k_cand,     dim3(157, 4), dim3(256), 0, stream, zb, (float4*)out, cid);
    hipLaunchKernelGGL(k_rescore,  dim3(2500),   dim3(256), 0, stream, z32, cid, out);
}

// Round 6
// 457.607 us; speedup vs baseline: 2.0149x; 1.3535x over previous
//
#include <hip/hip_runtime.h>
#include <hip/hip_bf16.h>
#include <math.h>
#include <float.h>

#define NROWS  10000
#define INDIM  512
#define KSPLIT 384     // OpenBLAS sgemm kc split (Round-3 passing arithmetic — do not touch)
#define HID    128
#define NSTRIP 4
#define STRIPW 2500
#define CHUNK  64
#define NCHUNK 40
#define CAP    512     // per-row candidate list capacity (mean ~290, +8 sigma slack)
#define NCNT   10048   // counter slots (covers pad rows up to 10047)
#define RESC   32      // exactly-rescored per row
#define KOUT   14
#define ZPADR  10064   // zb pad rows (max staged row 10059)
#define GRIDX  157
#define Z4TOT  25000000
#define Z4BLK  39809   // ceil(25e6 / 628)
#define Z4CHK  996     // ceil(Z4BLK / NCHUNK)
#define C_TAU  2.05f

using short8 = __attribute__((ext_vector_type(8))) short;
using f32x4  = __attribute__((ext_vector_type(4))) float;

// ---------------------------------------------------------------------------
// K1: bit-replicates numpy f32 (Round-3/4 passing arithmetic). Also zeroes the
// per-row append counters (replay-safe) and emits the bf16 copy of zhat.
// grid = 1258 x 128 (blocks 1250+ zero the zb pad rows).
// ---------------------------------------------------------------------------
__global__ __launch_bounds__(128)
void k_projnorm(const float* __restrict__ feat, const float* __restrict__ W,
                const float* __restrict__ b, float* __restrict__ z32,
                __hip_bfloat16* __restrict__ zb, int* __restrict__ cnt) {
    const int h = threadIdx.x;
    const int bx = blockIdx.x;
    if (bx < 79) {                       // zero cnt[0..10047] every launch
        const int i = bx * 128 + h;
        if (i < NCNT) cnt[i] = 0;
    }
    const int row0 = bx * 8;
    if (row0 >= NROWS) {                 // zero bf16 pad rows
#pragma unroll
        for (int r = 0; r < 8; ++r)
            if (row0 + r < ZPADR) zb[(size_t)(row0 + r) * HID + h] = __float2bfloat16(0.f);
        return;
    }
    float accA[8], accB[8];
#pragma unroll
    for (int r = 0; r < 8; ++r) { accA[r] = 0.f; accB[r] = 0.f; }
#pragma unroll 4
    for (int k4 = 0; k4 < 96; ++k4) {    // k = 0..383 (chain A)
        const int k = k4 * 4;
        const float w0 = W[(k + 0) * HID + h];
        const float w1 = W[(k + 1) * HID + h];
        const float w2 = W[(k + 2) * HID + h];
        const float w3 = W[(k + 3) * HID + h];
#pragma unroll
        for (int r = 0; r < 8; ++r) {
            const float4 f = *(const float4*)(feat + (size_t)(row0 + r) * INDIM + k);
            accA[r] = fmaf(f.x, w0, accA[r]);
            accA[r] = fmaf(f.y, w1, accA[r]);
            accA[r] = fmaf(f.z, w2, accA[r]);
            accA[r] = fmaf(f.w, w3, accA[r]);
        }
    }
#pragma unroll 4
    for (int k4 = 96; k4 < 128; ++k4) {  // k = 384..511 (chain B)
        const int k = k4 * 4;
        const float w0 = W[(k + 0) * HID + h];
        const float w1 = W[(k + 1) * HID + h];
        const float w2 = W[(k + 2) * HID + h];
        const float w3 = W[(k + 3) * HID + h];
#pragma unroll
        for (int r = 0; r < 8; ++r) {
            const float4 f = *(const float4*)(feat + (size_t)(row0 + r) * INDIM + k);
            accB[r] = fmaf(f.x, w0, accB[r]);
            accB[r] = fmaf(f.y, w1, accB[r]);
            accB[r] = fmaf(f.z, w2, accB[r]);
            accB[r] = fmaf(f.w, w3, accB[r]);
        }
    }
    __shared__ float zl[8][HID];
    __shared__ float nrm[8];
    const float bh = b[h];
#pragma unroll
    for (int r = 0; r < 8; ++r)
        zl[r][h] = __fadd_rn(__fadd_rn(accA[r], accB[r]), bh);
    __syncthreads();
    if (h < 8) {
        float rr[8];
#pragma unroll
        for (int j = 0; j < 8; ++j) rr[j] = __fmul_rn(zl[h][j], zl[h][j]);
        for (int i = 8; i < HID; i += 8)
#pragma unroll
            for (int j = 0; j < 8; ++j)
                rr[j] = __fadd_rn(rr[j], __fmul_rn(zl[h][i + j], zl[h][i + j]));
        const float s = __fadd_rn(
            __fadd_rn(__fadd_rn(rr[0], rr[1]), __fadd_rn(rr[2], rr[3])),
            __fadd_rn(__fadd_rn(rr[4], rr[5]), __fadd_rn(rr[6], rr[7])));
        nrm[h] = fmaxf(__fsqrt_rn(s), 1e-12f);
    }
    __syncthreads();
#pragma unroll
    for (int r = 0; r < 8; ++r) {
        const float v = __fdiv_rn(zl[r][h], nrm[r]);
        z32[(size_t)(row0 + r) * HID + h] = v;
        zb [(size_t)(row0 + r) * HID + h] = __float2bfloat16(v);
    }
}

// ---------------------------------------------------------------------------
// K2: swapped-operand bf16 MFMA + adaptive-threshold append + fused zeroing.
// Per chunk: stage next 64 j-rows (global->reg early, LDS write late), 16 mfma
// (lane owns 16 sim values of ONE row), running sigma-hat from sum(v^2),
// append values > tau to per-row global list, zero an output slice.
// Plain __syncthreads, one per chunk. grid = (157,4), block 256.
// ---------------------------------------------------------------------------
__global__ __launch_bounds__(256)
void k_cand(const __hip_bfloat16* __restrict__ zbp, float4* __restrict__ out4,
            int* __restrict__ cnt, unsigned int* __restrict__ list) {
    __shared__ ushort Bt[2][8192];      // 2 x 16 KB, swizzled [64 j][128 k] bf16
    const char* zbb = (const char*)zbp;
    const int tid = threadIdx.x, lane = tid & 63, wid = tid >> 6;
    const int row0 = blockIdx.x * 64;
    const int strip = blockIdx.y;
    const int jbase = strip * STRIPW;
    const int bid = strip * GRIDX + blockIdx.x;
    const int row_g = row0 + wid * 16 + (lane & 15);
    const int swz = (lane & 7) << 4;

    // A fragments (used as mfma B-operand): lane holds z[row_g][(l>>4)*8+ks*32..+8]
    short8 afr[4];
    {
        const char* ap = zbb + (size_t)row_g * 256 + ((lane >> 4) * 16);
        afr[0] = *(const short8*)(ap);
        afr[1] = *(const short8*)(ap + 64);
        afr[2] = *(const short8*)(ap + 128);
        afr[3] = *(const short8*)(ap + 192);
    }

    const int jl0 = wid * 16 + (lane >> 4);   // staging rows jl0, +4, +8, +12
    const int ir  = (lane & 15) * 16;         // in-row byte offset

    // prologue: stage chunk 0 -> buf 0
#pragma unroll
    for (int i = 0; i < 4; ++i) {
        const int jl = jl0 + i * 4;
        const uint4 d = *(const uint4*)(zbb + (size_t)(jbase + jl) * 256 + ir);
        *(uint4*)((char*)Bt[0] + (size_t)jl * 256 + (ir ^ ((jl & 7) << 4))) = d;
    }
    __syncthreads();

    const size_t zb0 = (size_t)bid * Z4BLK;
    int zlen = Z4TOT - (int)zb0; if (zlen > Z4BLK) zlen = Z4BLK;
    float4* zp = out4 + zb0;
    const float4 zero4 = make_float4(0.f, 0.f, 0.f, 0.f);

    float ss = 0.f;   // row-pooled sum of squared sims (n = 64*c samples)

#pragma unroll 1
    for (int c = 0; c < NCHUNK; ++c) {
        const int jc = c * CHUNK;
        const char* cur = (const char*)Bt[c & 1];

        // issue next-chunk global loads early
        uint4 st0, st1, st2, st3;
        const bool nx = (c + 1 < NCHUNK);
        if (nx) {
            const char* src = zbb + (size_t)(jbase + jc + CHUNK) * 256 + ir;
            st0 = *(const uint4*)(src + (size_t)(jl0 + 0)  * 256);
            st1 = *(const uint4*)(src + (size_t)(jl0 + 4)  * 256);
            st2 = *(const uint4*)(src + (size_t)(jl0 + 8)  * 256);
            st3 = *(const uint4*)(src + (size_t)(jl0 + 12) * 256);
        }

        // adaptive threshold for this chunk
        float tau;
        if (c == 0) tau = 0.10f;
        else {
            const float n = 64.f * (float)c;
            const float w = 1.f - 3.f * __frsqrt_rn(2.f * n);
            tau = fmaxf(C_TAU * w * __fsqrt_rn(ss / n), 0.08f);
        }

        // 16 mfma, swapped operands: lane owns output row i = row_g
        f32x4 acc[4];
#pragma unroll
        for (int t = 0; t < 4; ++t) {
            acc[t] = (f32x4){0.f, 0.f, 0.f, 0.f};
            const char* rp = cur + (size_t)(t * 16 + (lane & 15)) * 256;
#pragma unroll
            for (int ks = 0; ks < 4; ++ks) {
                const short8 bfr = *(const short8*)(rp + ((ks * 64 + (lane >> 4) * 16) ^ swz));
                acc[t] = __builtin_amdgcn_mfma_f32_16x16x32_bf16(bfr, afr[ks], acc[t], 0, 0, 0);
            }
        }

        // sigma accumulation + threshold append
        float ssl = 0.f;
#pragma unroll
        for (int t = 0; t < 4; ++t) {
#pragma unroll
            for (int r = 0; r < 4; ++r) {
                const float val = acc[t][r];
                const int js = jc + t * 16 + ((lane >> 4) << 2) + r;
                const int jg = jbase + js;
                const bool ok = (js < STRIPW) && (jg != row_g);
                ssl += ok ? val * val : 0.f;
                if (ok && val > tau) {
                    const unsigned int u = __builtin_bit_cast(unsigned int, val);
                    const unsigned int pk = (((u + 0x8000u) >> 16) << 16) | (unsigned int)jg;
                    const int pos = atomicAdd(&cnt[row_g], 1);
                    if (pos < CAP) list[(size_t)row_g * CAP + pos] = pk;
                }
            }
        }
        ssl += __shfl_xor(ssl, 16, 64);   // pool over the row's 4 lanes
        ssl += __shfl_xor(ssl, 32, 64);
        ss += ssl;

        // fused output zeroing slice
        {
            const int z0 = c * Z4CHK;
            int ze = z0 + Z4CHK; if (ze > zlen) ze = zlen;
            for (int i = z0 + tid; i < ze; i += 256) zp[i] = zero4;
        }

        // write staged regs -> other buffer
        if (nx) {
            char* wb = (char*)Bt[(c + 1) & 1];
            *(uint4*)(wb + (size_t)(jl0 + 0)  * 256 + (ir ^ (((jl0 + 0)  & 7) << 4))) = st0;
            *(uint4*)(wb + (size_t)(jl0 + 4)  * 256 + (ir ^ (((jl0 + 4)  & 7) << 4))) = st1;
            *(uint4*)(wb + (size_t)(jl0 + 8)  * 256 + (ir ^ (((jl0 + 8)  & 7) << 4))) = st2;
            *(uint4*)(wb + (size_t)(jl0 + 12) * 256 + (ir ^ (((jl0 + 12) & 7) << 4))) = st3;
        }
        __syncthreads();
    }
}

// ---------------------------------------------------------------------------
// K3: approx-top-32 of the appended list (packed uint keys), exact rescore of
// those 32 with the bit-exact sequential f32 FMA chain, exact top-14 by
// (value desc, idx asc), scatter. Rows pre-zeroed by K2.
// grid = 2500 (4 rows/block, 1 wave/row).
// ---------------------------------------------------------------------------
#define CE8(a, b) { const unsigned int x_ = k[a], y_ = k[b]; \
    k[a] = x_ > y_ ? x_ : y_; k[b] = x_ > y_ ? y_ : x_; }

__global__ __launch_bounds__(256)
void k_select(const float* __restrict__ z32, const int* __restrict__ cnt,
              const unsigned int* __restrict__ list, float* __restrict__ out) {
    __shared__ float zr[4][HID];
    const int tid = threadIdx.x, wid = tid >> 6, lane = tid & 63;
    const int row = blockIdx.x * 4 + wid;

    *(float2*)&zr[wid][lane * 2] = *(const float2*)(z32 + (size_t)row * HID + lane * 2);
    __syncthreads();

    int cn = cnt[row]; if (cn > CAP) cn = CAP;
    unsigned int k[8];
#pragma unroll
    for (int t = 0; t < 8; ++t) {
        const int p = t * 64 + lane;
        k[t] = (p < cn) ? list[(size_t)row * CAP + p] : 0u;
    }
    // Batcher sort-8 descending (19 CEs, static indices)
    CE8(0,1) CE8(2,3) CE8(4,5) CE8(6,7)
    CE8(0,2) CE8(1,3) CE8(4,6) CE8(5,7)
    CE8(1,2) CE8(5,6)
    CE8(0,4) CE8(1,5) CE8(2,6) CE8(3,7)
    CE8(2,4) CE8(3,5)
    CE8(1,2) CE8(3,4) CE8(5,6)

    // 32 pops by packed key (keys unique: idx in low bits); lane t keeps pop t
    unsigned int win = 0u;
#pragma unroll 1
    for (int t = 0; t < RESC; ++t) {
        unsigned int m = k[0];
#pragma unroll
        for (int msk = 1; msk <= 32; msk <<= 1) {
            const unsigned int o = (unsigned int)__shfl_xor((int)m, msk, 64);
            m = o > m ? o : m;
        }
        if (lane == t) win = m;
        if (k[0] == m && m != 0u) {
            k[0] = k[1]; k[1] = k[2]; k[2] = k[3]; k[3] = k[4];
            k[4] = k[5]; k[5] = k[6]; k[6] = k[7]; k[7] = 0u;
        }
    }

    // exact rescore (bit-exact Round-3 chain) of the 32 winners
    float ex = -INFINITY; int idx = 0x7fffffff;
    const bool act = (lane < RESC) && (win != 0u);
    if (act) {
        idx = (int)(win & 0xFFFFu);
        const float* p = z32 + (size_t)idx * HID;
        float a = 0.f;
#pragma unroll
        for (int k4 = 0; k4 < 32; ++k4) {   // strict k-ascending chain
            const float4 bb = *(const float4*)(p + k4 * 4);
            const float4 zz = *(const float4*)&zr[wid][k4 * 4];
            a = fmaf(zz.x, bb.x, a);
            a = fmaf(zz.y, bb.y, a);
            a = fmaf(zz.z, bb.z, a);
            a = fmaf(zz.w, bb.w, a);
        }
        ex = a;
    }

    bool alive = act;
#pragma unroll 1
    for (int t = 0; t < KOUT; ++t) {
        float mv = alive ? ex : -INFINITY;
        int   mi = alive ? idx : 0x7fffffff;
#pragma unroll
        for (int msk = 1; msk <= 32; msk <<= 1) {
            const float ov = __shfl_xor(mv, msk, 64);
            const int   oj = __shfl_xor(mi, msk, 64);
            const bool take = (ov > mv) || (ov == mv && oj < mi);
            mv = take ? ov : mv; mi = take ? oj : mi;
        }
        if (alive && idx == mi) {
            out[(size_t)row * NROWS + mi] = ex;
            alive = false;
        }
    }
}

// ---------------------------------------------------------------------------
extern "C" void kernel_launch(void* const* d_in, const int* in_sizes, int n_in,
                              void* d_out, int out_size, void* d_ws, size_t ws_size,
                              hipStream_t stream) {
    const float* feat = (const float*)d_in[0];
    const float* W    = (const float*)d_in[1];
    const float* b    = (const float*)d_in[2];
    float* out = (float*)d_out;

    char* ws = (char*)d_ws;
    float*          z32 = (float*)ws;                          //  5,120,000 B
    __hip_bfloat16* zb  = (__hip_bfloat16*)(ws + 5120000);     //  2,576,384 B (10064x256)
    int*            cnt = (int*)(ws + 7696384);                //     40,192 B (10048)
    unsigned int*   lst = (unsigned int*)(ws + 7736576);       // 20,578,304 B (10048x512x4)

    hipLaunchKernelGGL(k_projnorm, dim3(1258),     dim3(128), 0, stream, feat, W, b, z32, zb, cnt);
    hipLaunchKernelGGL(k_cand,     dim3(GRIDX, 4), dim3(256), 0, stream, zb, (float4*)out, cnt, lst);
    hipLaunchKernelGGL(k_select,   dim3(2500),     dim3(256), 0, stream, z32, cnt, lst, out);
}

// Round 7
// 287.626 us; speedup vs baseline: 3.2057x; 1.5910x over previous
//
#include <hip/hip_runtime.h>
#include <hip/hip_bf16.h>
#include <math.h>
#include <float.h>

#define NROWS  10000
#define INDIM  512
#define KSPLIT 384     // OpenBLAS sgemm kc split (Round-3 passing arithmetic — do not touch)
#define HID    128
#define NSTRIP 8
#define STRIPW 1250
#define CHUNK  64
#define NCHUNK 20      // 20*64 = 1280 >= 1250
#define CAPS   96      // per-(row,strip) segment capacity (mean ~44, +7.9 sigma)
#define RESC   32      // exactly-rescored per row
#define KOUT   14
#define ZPADR  10064   // zb pad rows (max staged row 10029, max A row 10047)
#define GRIDX  157
#define NBLK   1256    // GRIDX * NSTRIP
#define Z4TOT  25000000
#define Z4BLK  19905   // ceil(25e6 / 1256)
#define Z4CHK  996     // ceil(Z4BLK / NCHUNK)
#define C_TAU  2.05f

using short8 = __attribute__((ext_vector_type(8))) short;
using f32x4  = __attribute__((ext_vector_type(4))) float;

// ---------------------------------------------------------------------------
// K1: bit-replicates numpy f32 (Round-3 passing arithmetic). Emits z32 + bf16
// copy. grid = 1258 x 128 (blocks 1250+ zero the zb pad rows).
// ---------------------------------------------------------------------------
__global__ __launch_bounds__(128)
void k_projnorm(const float* __restrict__ feat, const float* __restrict__ W,
                const float* __restrict__ b, float* __restrict__ z32,
                __hip_bfloat16* __restrict__ zb) {
    const int h = threadIdx.x;
    const int row0 = blockIdx.x * 8;
    if (row0 >= NROWS) {                 // zero bf16 pad rows
#pragma unroll
        for (int r = 0; r < 8; ++r)
            if (row0 + r < ZPADR) zb[(size_t)(row0 + r) * HID + h] = __float2bfloat16(0.f);
        return;
    }
    float accA[8], accB[8];
#pragma unroll
    for (int r = 0; r < 8; ++r) { accA[r] = 0.f; accB[r] = 0.f; }
#pragma unroll 4
    for (int k4 = 0; k4 < 96; ++k4) {    // k = 0..383 (chain A)
        const int k = k4 * 4;
        const float w0 = W[(k + 0) * HID + h];
        const float w1 = W[(k + 1) * HID + h];
        const float w2 = W[(k + 2) * HID + h];
        const float w3 = W[(k + 3) * HID + h];
#pragma unroll
        for (int r = 0; r < 8; ++r) {
            const float4 f = *(const float4*)(feat + (size_t)(row0 + r) * INDIM + k);
            accA[r] = fmaf(f.x, w0, accA[r]);
            accA[r] = fmaf(f.y, w1, accA[r]);
            accA[r] = fmaf(f.z, w2, accA[r]);
            accA[r] = fmaf(f.w, w3, accA[r]);
        }
    }
#pragma unroll 4
    for (int k4 = 96; k4 < 128; ++k4) {  // k = 384..511 (chain B)
        const int k = k4 * 4;
        const float w0 = W[(k + 0) * HID + h];
        const float w1 = W[(k + 1) * HID + h];
        const float w2 = W[(k + 2) * HID + h];
        const float w3 = W[(k + 3) * HID + h];
#pragma unroll
        for (int r = 0; r < 8; ++r) {
            const float4 f = *(const float4*)(feat + (size_t)(row0 + r) * INDIM + k);
            accB[r] = fmaf(f.x, w0, accB[r]);
            accB[r] = fmaf(f.y, w1, accB[r]);
            accB[r] = fmaf(f.z, w2, accB[r]);
            accB[r] = fmaf(f.w, w3, accB[r]);
        }
    }
    __shared__ float zl[8][HID];
    __shared__ float nrm[8];
    const float bh = b[h];
#pragma unroll
    for (int r = 0; r < 8; ++r)
        zl[r][h] = __fadd_rn(__fadd_rn(accA[r], accB[r]), bh);
    __syncthreads();
    if (h < 8) {
        float rr[8];
#pragma unroll
        for (int j = 0; j < 8; ++j) rr[j] = __fmul_rn(zl[h][j], zl[h][j]);
        for (int i = 8; i < HID; i += 8)
#pragma unroll
            for (int j = 0; j < 8; ++j)
                rr[j] = __fadd_rn(rr[j], __fmul_rn(zl[h][i + j], zl[h][i + j]));
        const float s = __fadd_rn(
            __fadd_rn(__fadd_rn(rr[0], rr[1]), __fadd_rn(rr[2], rr[3])),
            __fadd_rn(__fadd_rn(rr[4], rr[5]), __fadd_rn(rr[6], rr[7])));
        nrm[h] = fmaxf(__fsqrt_rn(s), 1e-12f);
    }
    __syncthreads();
#pragma unroll
    for (int r = 0; r < 8; ++r) {
        const float v = __fdiv_rn(zl[r][h], nrm[r]);
        z32[(size_t)(row0 + r) * HID + h] = v;
        zb [(size_t)(row0 + r) * HID + h] = __float2bfloat16(v);
    }
}

// ---------------------------------------------------------------------------
// K2: swapped-operand bf16 MFMA + adaptive threshold + LDS-counter append.
// Each block exclusively owns its 64 (row, strip) segments -> append position
// from an LDS atomic (no global round-trip), global store fire-and-forget.
// Zero-stores issued at top of chunk body (drain under compute).
// grid = (157, 8), block 256.
// ---------------------------------------------------------------------------
__global__ __launch_bounds__(256)
void k_cand(const __hip_bfloat16* __restrict__ zbp, float4* __restrict__ out4,
            int* __restrict__ cnt4, unsigned int* __restrict__ list) {
    __shared__ ushort Bt[2][8192];      // 2 x 16 KB, swizzled [64 j][128 k] bf16
    __shared__ int lcnt[64];            // per-row append counters
    const char* zbb = (const char*)zbp;
    const int tid = threadIdx.x, lane = tid & 63, wid = tid >> 6;
    const int row0 = blockIdx.x * 64;
    const int strip = blockIdx.y;
    const int jbase = strip * STRIPW;
    const int bid = strip * GRIDX + blockIdx.x;
    const int row_g = row0 + wid * 16 + (lane & 15);
    const int rloc  = wid * 16 + (lane & 15);
    const int swz = (lane & 7) << 4;

    if (tid < 64) lcnt[tid] = 0;

    // A fragments (used as mfma B-operand): lane holds z[row_g][(l>>4)*8+ks*32..+8]
    short8 afr[4];
    {
        const char* ap = zbb + (size_t)row_g * 256 + ((lane >> 4) * 16);
        afr[0] = *(const short8*)(ap);
        afr[1] = *(const short8*)(ap + 64);
        afr[2] = *(const short8*)(ap + 128);
        afr[3] = *(const short8*)(ap + 192);
    }

    const int jl0 = wid * 16 + (lane >> 4);   // staging rows jl0, +4, +8, +12
    const int ir  = (lane & 15) * 16;         // in-row byte offset

    // prologue: stage chunk 0 -> buf 0
#pragma unroll
    for (int i = 0; i < 4; ++i) {
        const int jl = jl0 + i * 4;
        const uint4 d = *(const uint4*)(zbb + (size_t)(jbase + jl) * 256 + ir);
        *(uint4*)((char*)Bt[0] + (size_t)jl * 256 + (ir ^ ((jl & 7) << 4))) = d;
    }
    __syncthreads();

    const size_t zb0 = (size_t)bid * Z4BLK;
    int zlen = Z4TOT - (int)zb0; if (zlen > Z4BLK) zlen = Z4BLK;
    float4* zp = out4 + zb0;
    const float4 zero4 = make_float4(0.f, 0.f, 0.f, 0.f);

    float ss = 0.f;   // row-pooled sum of squared sims (n = 64*c samples)

#pragma unroll 1
    for (int c = 0; c < NCHUNK; ++c) {
        const int jc = c * CHUNK;
        const char* cur = (const char*)Bt[c & 1];

        // issue next-chunk global loads early
        uint4 st0, st1, st2, st3;
        const bool nx = (c + 1 < NCHUNK);
        if (nx) {
            const char* src = zbb + (size_t)(jbase + jc + CHUNK) * 256 + ir;
            st0 = *(const uint4*)(src + (size_t)(jl0 + 0)  * 256);
            st1 = *(const uint4*)(src + (size_t)(jl0 + 4)  * 256);
            st2 = *(const uint4*)(src + (size_t)(jl0 + 8)  * 256);
            st3 = *(const uint4*)(src + (size_t)(jl0 + 12) * 256);
        }

        // fused output zeroing slice (issued early: drains under compute)
        {
            const int z0 = c * Z4CHK;
            int ze = z0 + Z4CHK; if (ze > zlen) ze = zlen;
            for (int i = z0 + tid; i < ze; i += 256) zp[i] = zero4;
        }

        // adaptive threshold for this chunk
        float tau;
        if (c == 0) tau = 0.10f;
        else {
            const float n = 64.f * (float)c;
            const float w = 1.f - 3.f * __frsqrt_rn(2.f * n);
            tau = fmaxf(C_TAU * w * __fsqrt_rn(ss / n), 0.08f);
        }

        // 16 mfma, swapped operands: lane owns output row row_g
        f32x4 acc[4];
#pragma unroll
        for (int t = 0; t < 4; ++t) {
            acc[t] = (f32x4){0.f, 0.f, 0.f, 0.f};
            const char* rp = cur + (size_t)(t * 16 + (lane & 15)) * 256;
#pragma unroll
            for (int ks = 0; ks < 4; ++ks) {
                const short8 bfr = *(const short8*)(rp + ((ks * 64 + (lane >> 4) * 16) ^ swz));
                acc[t] = __builtin_amdgcn_mfma_f32_16x16x32_bf16(bfr, afr[ks], acc[t], 0, 0, 0);
            }
        }

        // sigma accumulation + LDS-counter append (store is fire-and-forget)
        float ssl = 0.f;
#pragma unroll
        for (int t = 0; t < 4; ++t) {
#pragma unroll
            for (int r = 0; r < 4; ++r) {
                const float val = acc[t][r];
                const int js = jc + t * 16 + ((lane >> 4) << 2) + r;
                const int jg = jbase + js;
                const bool ok = (js < STRIPW) && (jg != row_g);
                ssl += ok ? val * val : 0.f;
                if (ok && val > tau) {
                    const unsigned int u = __builtin_bit_cast(unsigned int, val);
                    const unsigned int pk = (((u + 0x8000u) >> 16) << 16) | (unsigned int)jg;
                    const int pos = atomicAdd(&lcnt[rloc], 1);
                    if (pos < CAPS)
                        list[((size_t)row_g * NSTRIP + strip) * CAPS + pos] = pk;
                }
            }
        }
        ssl += __shfl_xor(ssl, 16, 64);   // pool over the row's 4 lanes
        ssl += __shfl_xor(ssl, 32, 64);
        ss += ssl;

        // write staged regs -> other buffer
        if (nx) {
            char* wb = (char*)Bt[(c + 1) & 1];
            *(uint4*)(wb + (size_t)(jl0 + 0)  * 256 + (ir ^ (((jl0 + 0)  & 7) << 4))) = st0;
            *(uint4*)(wb + (size_t)(jl0 + 4)  * 256 + (ir ^ (((jl0 + 4)  & 7) << 4))) = st1;
            *(uint4*)(wb + (size_t)(jl0 + 8)  * 256 + (ir ^ (((jl0 + 8)  & 7) << 4))) = st2;
            *(uint4*)(wb + (size_t)(jl0 + 12) * 256 + (ir ^ (((jl0 + 12) & 7) << 4))) = st3;
        }
        __syncthreads();
    }

    // flush per-(row, strip) counts (this block is the exclusive owner)
    if (tid < 64) {
        const int row = row0 + tid;
        if (row < NROWS) cnt4[row * NSTRIP + strip] = lcnt[tid];
    }
}

// ---------------------------------------------------------------------------
// K3: approx-top-32 of the 8 per-strip segments (packed bf16|idx keys,
// bitonic-16/lane over 768 slots), exact rescore of those 32 with the
// bit-exact sequential f32 FMA chain, exact top-14 by (value desc, idx asc),
// scatter. Rows pre-zeroed by K2. grid = 2500 (4 rows/block, 1 wave/row).
// ---------------------------------------------------------------------------
#define CEK(a, b) { const unsigned int x_ = k[a], y_ = k[b]; \
    k[a] = x_ > y_ ? x_ : y_; k[b] = x_ > y_ ? y_ : x_; }

__global__ __launch_bounds__(256)
void k_select(const float* __restrict__ z32, const int* __restrict__ cnt4,
              const unsigned int* __restrict__ list, float* __restrict__ out) {
    __shared__ float zr[4][HID];
    const int tid = threadIdx.x, wid = tid >> 6, lane = tid & 63;
    const int row = blockIdx.x * 4 + wid;

    *(float2*)&zr[wid][lane * 2] = *(const float2*)(z32 + (size_t)row * HID + lane * 2);
    __syncthreads();

    unsigned int k[16];
#pragma unroll
    for (int t = 0; t < 12; ++t) {
        const int p = t * 64 + lane;          // 0..767
        const int seg = p / CAPS;             // 0..7
        const int off = p - seg * CAPS;
        int cn = cnt4[row * NSTRIP + seg]; if (cn > CAPS) cn = CAPS;
        k[t] = (off < cn) ? list[((size_t)row * NSTRIP + seg) * CAPS + off] : 0u;
    }
#pragma unroll
    for (int t = 12; t < 16; ++t) k[t] = 0u;

    // bitonic sort-16 descending (static indices, sentinel 0)
#pragma unroll
    for (int size = 2; size <= 16; size <<= 1) {
#pragma unroll
        for (int stride = size >> 1; stride > 0; stride >>= 1) {
#pragma unroll
            for (int i = 0; i < 16; ++i) {
                const int j = i ^ stride;
                if (j > i) {
                    if ((i & size) == 0) { CEK(i, j); } else { CEK(j, i); }
                }
            }
        }
    }

    // 32 pops by packed key (keys unique: idx in low bits); lane t keeps pop t
    unsigned int win = 0u;
#pragma unroll 1
    for (int t = 0; t < RESC; ++t) {
        unsigned int m = k[0];
#pragma unroll
        for (int msk = 1; msk <= 32; msk <<= 1) {
            const unsigned int o = (unsigned int)__shfl_xor((int)m, msk, 64);
            m = o > m ? o : m;
        }
        if (lane == t) win = m;
        if (k[0] == m && m != 0u) {
#pragma unroll
            for (int s = 0; s < 15; ++s) k[s] = k[s + 1];
            k[15] = 0u;
        }
    }

    // exact rescore (bit-exact Round-3 chain) of the 32 winners
    float ex = -INFINITY; int idx = 0x7fffffff;
    const bool act = (lane < RESC) && (win != 0u);
    if (act) {
        idx = (int)(win & 0xFFFFu);
        const float* p = z32 + (size_t)idx * HID;
        float a = 0.f;
#pragma unroll
        for (int k4 = 0; k4 < 32; ++k4) {   // strict k-ascending chain
            const float4 bb = *(const float4*)(p + k4 * 4);
            const float4 zz = *(const float4*)&zr[wid][k4 * 4];
            a = fmaf(zz.x, bb.x, a);
            a = fmaf(zz.y, bb.y, a);
            a = fmaf(zz.z, bb.z, a);
            a = fmaf(zz.w, bb.w, a);
        }
        ex = a;
    }

    bool alive = act;
#pragma unroll 1
    for (int t = 0; t < KOUT; ++t) {
        float mv = alive ? ex : -INFINITY;
        int   mi = alive ? idx : 0x7fffffff;
#pragma unroll
        for (int msk = 1; msk <= 32; msk <<= 1) {
            const float ov = __shfl_xor(mv, msk, 64);
            const int   oj = __shfl_xor(mi, msk, 64);
            const bool take = (ov > mv) || (ov == mv && oj < mi);
            mv = take ? ov : mv; mi = take ? oj : mi;
        }
        if (alive && idx == mi) {
            out[(size_t)row * NROWS + mi] = ex;
            alive = false;
        }
    }
}

// ---------------------------------------------------------------------------
extern "C" void kernel_launch(void* const* d_in, const int* in_sizes, int n_in,
                              void* d_out, int out_size, void* d_ws, size_t ws_size,
                              hipStream_t stream) {
    const float* feat = (const float*)d_in[0];
    const float* W    = (const float*)d_in[1];
    const float* b    = (const float*)d_in[2];
    float* out = (float*)d_out;

    char* ws = (char*)d_ws;
    float*          z32  = (float*)ws;                          //  5,120,000 B
    __hip_bfloat16* zb   = (__hip_bfloat16*)(ws + 5120000);     //  2,576,384 B (10064x256)
    int*            cnt4 = (int*)(ws + 7696384);                //    320,000 B (10000x8)
    unsigned int*   lst  = (unsigned int*)(ws + 8016384);       // 30,720,000 B (10000x8x96x4)

    hipLaunchKernelGGL(k_projnorm, dim3(1258),         dim3(128), 0, stream, feat, W, b, z32, zb);
    hipLaunchKernelGGL(k_cand,     dim3(GRIDX, NSTRIP), dim3(256), 0, stream, zb, (float4*)out, cnt4, lst);
    hipLaunchKernelGGL(k_select,   dim3(2500),          dim3(256), 0, stream, z32, cnt4, lst, out);
}